// Round 4
// baseline (165.887 us; speedup 1.0000x reference)
//
#include <hip/hip_runtime.h>
#include <hip/hip_bf16.h>

#define BB   8
#define CIN  512
#define COUT 512
#define ZD   512
#define HH   64
#define WW   64

#define MOD_SCALE  0.04419417382415922f    // 1/sqrt(512)
#define CONV_SCALE 0.014731391274719742f   // 1/sqrt(512*9)

typedef __bf16 bf16x8 __attribute__((ext_vector_type(8)));
typedef float  f32x4  __attribute__((ext_vector_type(4)));
typedef float  f32x16 __attribute__((ext_vector_type(16)));

static __device__ __forceinline__ unsigned short f32_to_bf16_rne(float f) {
    unsigned int u = __float_as_uint(f);
    u = (u + 0x7FFFu + ((u >> 16) & 1u)) >> 16;
    return (unsigned short)u;
}

// ---------------- K0: sconv[b][i] = (style[b]·mod_w[i]*MOD_SCALE + mod_b[i]) * CONV_SCALE
__global__ void k_style(const float* __restrict__ style, const float* __restrict__ mod_w,
                        const float* __restrict__ mod_b, float* __restrict__ sconv) {
    int wid  = blockIdx.x * 4 + (threadIdx.x >> 6);   // 0..4095 = b*512+i
    int lane = threadIdx.x & 63;
    int b = wid >> 9;
    int i = wid & 511;
    const float4* st = (const float4*)(style + (size_t)b * ZD);
    const float4* mw = (const float4*)(mod_w + (size_t)i * ZD);
    float4 a0 = st[lane],      b0 = mw[lane];
    float4 a1 = st[lane + 64], b1 = mw[lane + 64];
    float sum = a0.x*b0.x + a0.y*b0.y + a0.z*b0.z + a0.w*b0.w
              + a1.x*b1.x + a1.y*b1.y + a1.z*b1.z + a1.w*b1.w;
    #pragma unroll
    for (int off = 32; off > 0; off >>= 1) sum += __shfl_down(sum, off);
    if (lane == 0) sconv[wid] = (sum * MOD_SCALE + mod_b[i]) * CONV_SCALE;
}

// ---------------- K1: zero the 1-px border of padded xs2p [8][66][66][512] bf16
__global__ void k_zero_border(unsigned short* __restrict__ xs2p) {
    int b = blockIdx.y;
    int p = blockIdx.x * 4 + (threadIdx.x >> 6);   // 0..259
    int lane = threadIdx.x & 63;
    int h, w;
    if (p < 66)       { h = 0;       w = p; }
    else if (p < 132) { h = 65;      w = p - 66; }
    else if (p < 196) { h = p - 131; w = 0; }      // rows 1..64
    else              { h = p - 195; w = 65; }
    int4 z = {0, 0, 0, 0};
    *(int4*)&xs2p[((size_t)(b * 66 + h) * 66 + w) * 512 + lane * 8] = z;
}

// ---------------- K2: xs2p[b][h+1][w+1][i] = bf16(input[b][i][h][w] * sconv[b][i])
__global__ void k_scale_input(const float* __restrict__ input, const float* __restrict__ sconv,
                              unsigned short* __restrict__ xs2p) {
    int i0 = blockIdx.x * 32;
    int h  = blockIdx.y;
    int b  = blockIdx.z;
    __shared__ unsigned short lds[64][40];   // [w][ii], padded row
    #pragma unroll
    for (int r = 0; r < 8; ++r) {
        int ii = r * 4 + (threadIdx.x >> 6);
        int w  = threadIdx.x & 63;
        float v = input[(((size_t)b * CIN + i0 + ii) * HH + h) * WW + w];
        float s = sconv[b * CIN + i0 + ii];
        lds[w][ii] = f32_to_bf16_rne(v * s);
    }
    __syncthreads();
    int w = threadIdx.x >> 2, q = threadIdx.x & 3;
    int4 val = *(const int4*)&lds[w][q * 8];
    *(int4*)&xs2p[((size_t)(b * 66 + h + 1) * 66 + (w + 1)) * 512 + i0 + q * 8] = val;
}

// ---------------- K3: w3 ts-linear weights. ts = c*9+tap.
// byte addr = ts*32768 + half*16384 + (g*256 + oc_low)*16 ; elem += i&7
__global__ void k_weight(const float* __restrict__ weight, unsigned short* __restrict__ w3) {
    int t = blockIdx.x * 256 + threadIdx.x;   // 0 .. 512*512-1 : o*512 + i
    int o = t >> 9, i = t & 511;
    int c = i >> 5, g = (i >> 3) & 3, il = i & 7;
    int h = o >> 8, ol = o & 255;
    const float* src = weight + ((size_t)o * CIN + i) * 9;
    #pragma unroll
    for (int p = 0; p < 9; ++p) {
        size_t gran = ((size_t)(c * 9 + p) * 2 + h) * 1024 + g * 256 + ol;
        w3[gran * 8 + il] = f32_to_bf16_rne(src[p]);
    }
}

// ---------------- K4: main conv. 512 thr / 8 waves. Tile 256 OC x (4 rows x 64 px).
// Wave tile 128oc x 64px = 4mt x 2nt tiles of 32x32, K-step 16ch (2 halves per ts).
// LDS: W 4x16KB rotating (lead 3) + X 2x32KB = 128KB. 2 barriers/ts, reg-pipelined frags.
#define GLD(srcp, ldsbyte)                                                        \
    __builtin_amdgcn_global_load_lds(                                             \
        (const __attribute__((address_space(1))) unsigned int*)(srcp),            \
        (__attribute__((address_space(3))) unsigned int*)(smb + (ldsbyte)),       \
        16, 0, 0)

#define MFMA8(Af, Bf)                                                             \
    _Pragma("unroll") for (int mt = 0; mt < 4; ++mt)                              \
        _Pragma("unroll") for (int nt = 0; nt < 2; ++nt)                          \
            acc[mt][nt] = __builtin_amdgcn_mfma_f32_32x32x16_bf16(                \
                Af[mt], Bf[nt], acc[mt][nt], 0, 0, 0);

#define TAP(t, Nmid, DOX, DOW, LASTTS) {                                          \
    const int kh0 = (t) / 3, kw0 = (t) % 3;                                       \
    const int tn  = ((t) + 1) % 9;                                                \
    const int kh1 = tn / 3, kw1 = tn % 3;                                         \
    const int wnx = (wrd + 16384) & 65535;                                        \
    const int wwr = (wrd + 49152) & 65535;                                        \
    const int xrdn = ((t) == 8) ? (xrd ^ 32768) : xrd;                            \
    /* ---------- half 0 (ks=0, set A) ---------- */                              \
    if ((DOX) && (t) == 0) GLD(sxn +  0, xwr + 0 * 8192 + wdst);                  \
    if ((DOX) && (t) == 1) GLD(sxn + 32, xwr + 2 * 8192 + wdst);                  \
    if (DOW) GLD(pW, wwr + wdst);                                                 \
    {   const char* wb = smb + wrd + 8192 + aoff;                                 \
        const char* xb = smb + xrd + 16384 + boff + kh0 * 1056 + kw0 * 16;        \
        aB[0] = *(const bf16x8*)(wb);        aB[1] = *(const bf16x8*)(wb + 512);  \
        aB[2] = *(const bf16x8*)(wb + 1024); aB[3] = *(const bf16x8*)(wb + 1536); \
        bB[0] = *(const bf16x8*)(xb);        bB[1] = *(const bf16x8*)(xb + 512);  \
    }                                                                             \
    __builtin_amdgcn_s_setprio(1);                                                \
    MFMA8(aA, bA)                                                                 \
    __builtin_amdgcn_s_setprio(0);                                                \
    asm volatile("s_waitcnt vmcnt(" #Nmid ")" ::: "memory");                      \
    __builtin_amdgcn_s_barrier();                                                 \
    /* ---------- half 1 (ks=1, set B) ---------- */                              \
    if ((DOX) && (t) == 0) GLD(sxn + 16, xwr + 1 * 8192 + wdst);                  \
    if ((DOX) && (t) == 1) GLD(sxn + 48, xwr + 3 * 8192 + wdst);                  \
    if (DOW) { GLD(pW + 8192, wwr + 8192 + wdst); pW += 32768; }                  \
    if (!(LASTTS)) {                                                              \
        const char* wb = smb + wnx + aoff;                                        \
        const char* xb = smb + xrdn + boff + kh1 * 1056 + kw1 * 16;               \
        aA[0] = *(const bf16x8*)(wb);        aA[1] = *(const bf16x8*)(wb + 512);  \
        aA[2] = *(const bf16x8*)(wb + 1024); aA[3] = *(const bf16x8*)(wb + 1536); \
        bA[0] = *(const bf16x8*)(xb);        bA[1] = *(const bf16x8*)(xb + 512);  \
    }                                                                             \
    __builtin_amdgcn_s_setprio(1);                                                \
    MFMA8(aB, bB)                                                                 \
    __builtin_amdgcn_s_setprio(0);                                                \
    __builtin_amdgcn_s_barrier();                                                 \
    wrd = wnx;                                                                    \
}

__global__ __launch_bounds__(512, 2)
void k_conv(const unsigned short* __restrict__ xs2p, const unsigned short* __restrict__ w3,
            float* __restrict__ out) {
    __shared__ unsigned short smem[65536];   // 131072 bytes: W 0..64K, X 64K..128K
    char* smb = (char*)smem;

    const int tid  = threadIdx.x;
    const int wid  = tid >> 6, lane = tid & 63;
    const int wm   = wid >> 2, wr   = wid & 3;
    const int l31  = lane & 31, l5  = lane >> 5;
    const int half = blockIdx.x;              // 0,1 -> oc0 = half*256
    const int oc0  = half * 256;
    const int y0   = blockIdx.y * 4;
    const int b    = blockIdx.z;

    const int p_lin = wid * 64 + lane;               // 0..511
    const int xrow  = p_lin / 66;
    const int xcol  = p_lin - xrow * 66;
    const char* srcX = (const char*)xs2p;
    if (p_lin < 396)
        srcX += ((size_t)(b * 66 + y0 + xrow) * 66 + xcol) * 1024;  // 1KB per pixel

    const char* pW0 = (const char*)w3 + (size_t)half * 16384 + p_lin * 16;
    const int wdst = p_lin * 16;                     // wave-linear LDS slice

    // ---- prologue: X planes of chunk0, then W ts0,ts1,ts2 (FIFO order matters)
    GLD(srcX +  0, 65536 + 0 * 8192 + wdst);
    GLD(srcX + 16, 65536 + 1 * 8192 + wdst);
    GLD(srcX + 32, 65536 + 2 * 8192 + wdst);
    GLD(srcX + 48, 65536 + 3 * 8192 + wdst);
    GLD(pW0,          0     + wdst);
    GLD(pW0 +  8192,  8192  + wdst);
    GLD(pW0 + 32768,  16384 + wdst);
    GLD(pW0 + 40960,  24576 + wdst);
    GLD(pW0 + 65536,  32768 + wdst);
    GLD(pW0 + 73728,  40960 + wdst);
    const char* pW = pW0 + 3 * 32768;                // -> W(ts=3)
    asm volatile("s_waitcnt vmcnt(4)" ::: "memory"); // X + W0 landed; W1,W2 in flight
    __builtin_amdgcn_s_barrier();

    f32x16 acc[4][2];
    #pragma unroll
    for (int mt = 0; mt < 4; ++mt)
        #pragma unroll
        for (int nt = 0; nt < 2; ++nt)
            acc[mt][nt] = (f32x16)(0.f);

    const int aoff = l5 * 4096 + (wm * 128 + l31) * 16;   // W frag base (bytes)
    const int boff = l5 * 8192 + (wr * 66 + l31) * 16;    // X frag base (bytes)

    bf16x8 aA[4], bA[2], aB[4], bB[2];
    int wrd = 0;             // W read buf = (ts&3)*16384
    int xrd = 65536;         // X read buf
    const char* sxn = srcX + 64;

    // pre-read set A = (ts0, ks0): W0 granules 0/1, X chunk0, tap0 (kh=kw=0)
    {
        const char* wb = smb + aoff;
        const char* xb = smb + 65536 + boff;
        aA[0] = *(const bf16x8*)(wb);        aA[1] = *(const bf16x8*)(wb + 512);
        aA[2] = *(const bf16x8*)(wb + 1024); aA[3] = *(const bf16x8*)(wb + 1536);
        bA[0] = *(const bf16x8*)(xb);        bA[1] = *(const bf16x8*)(xb + 512);
    }

    for (int c = 0; c < 15; ++c) {
        const int xwr = xrd ^ 32768;
        TAP(0, 4, 1, 1, 0) TAP(1, 6, 1, 1, 0) TAP(2, 5, 0, 1, 0)
        TAP(3, 3, 0, 1, 0) TAP(4, 3, 0, 1, 0) TAP(5, 3, 0, 1, 0)
        TAP(6, 3, 0, 1, 0) TAP(7, 3, 0, 1, 0) TAP(8, 3, 0, 1, 0)
        sxn += 64; xrd ^= 32768;
    }
    {   // c = 15 tail: no X prefetch; W last issued during tap5 (W143)
        const int xwr = 0; (void)xwr;
        TAP(0, 3, 0, 1, 0) TAP(1, 3, 0, 1, 0) TAP(2, 3, 0, 1, 0)
        TAP(3, 3, 0, 1, 0) TAP(4, 3, 0, 1, 0) TAP(5, 3, 0, 1, 0)
        TAP(6, 2, 0, 0, 0) TAP(7, 0, 0, 0, 0) TAP(8, 0, 0, 0, 1)
    }

    // ---- epilogue: 32x32 C/D layout: col=lane&31, row=(reg&3)+8*(reg>>2)+4*(lane>>5)
    const int ybase = (y0 + wr) * 64;
    #pragma unroll
    for (int mt = 0; mt < 4; ++mt)
        #pragma unroll
        for (int nt = 0; nt < 2; ++nt)
            #pragma unroll
            for (int r = 0; r < 16; ++r) {
                int row = (r & 3) + 8 * (r >> 2) + 4 * l5;
                int oc  = oc0 + wm * 128 + mt * 32 + row;
                out[((size_t)(b * COUT + oc) << 12) + ybase + nt * 32 + l31] = acc[mt][nt][r];
            }
}

extern "C" void kernel_launch(void* const* d_in, const int* in_sizes, int n_in,
                              void* d_out, int out_size, void* d_ws, size_t ws_size,
                              hipStream_t stream) {
    const float* input  = (const float*)d_in[0];
    const float* style  = (const float*)d_in[1];
    const float* weight = (const float*)d_in[2];
    const float* mod_w  = (const float*)d_in[3];
    const float* mod_b  = (const float*)d_in[4];
    float* out = (float*)d_out;

    const size_t xs2p_bytes = (size_t)BB * 66 * 66 * 512 * 2;   // 35,684,352
    const size_t w3_bytes   = (size_t)144 * 2 * 1024 * 8 * 2;   // 4,718,592
    const size_t need = 16384 + xs2p_bytes + w3_bytes;
    if (ws_size < need) return;   // leave output poisoned -> clear failure

    float*          sconv = (float*)d_ws;
    unsigned short* xs2p  = (unsigned short*)((char*)d_ws + 16384);
    unsigned short* w3    = (unsigned short*)((char*)d_ws + 16384 + xs2p_bytes);

    hipLaunchKernelGGL(k_style,       dim3(1024),      dim3(256), 0, stream, style, mod_w, mod_b, sconv);
    hipLaunchKernelGGL(k_weight,      dim3(1024),      dim3(256), 0, stream, weight, w3);
    hipLaunchKernelGGL(k_zero_border, dim3(65, 8),     dim3(256), 0, stream, xs2p);
    hipLaunchKernelGGL(k_scale_input, dim3(16, 64, 8), dim3(256), 0, stream, input, sconv, xs2p);
    hipLaunchKernelGGL(k_conv,        dim3(2, 16, 8),  dim3(512), 0, stream, xs2p, w3, out);
}

// Round 5
// 164.149 us; speedup vs baseline: 1.0106x; 1.0106x over previous
//
#include <hip/hip_runtime.h>
#include <hip/hip_bf16.h>

#define BB   8
#define CIN  512
#define COUT 512
#define ZD   512
#define HH   64
#define WW   64

#define MOD_SCALE  0.04419417382415922f    // 1/sqrt(512)
#define CONV_SCALE 0.014731391274719742f   // 1/sqrt(512*9)

typedef __bf16 bf16x8 __attribute__((ext_vector_type(8)));
typedef float  f32x4  __attribute__((ext_vector_type(4)));
typedef float  f32x16 __attribute__((ext_vector_type(16)));

static __device__ __forceinline__ unsigned short f32_to_bf16_rne(float f) {
    unsigned int u = __float_as_uint(f);
    u = (u + 0x7FFFu + ((u >> 16) & 1u)) >> 16;
    return (unsigned short)u;
}

// ---------------- K0: sconv[b][i] = (style[b]·mod_w[i]*MOD_SCALE + mod_b[i]) * CONV_SCALE
__global__ void k_style(const float* __restrict__ style, const float* __restrict__ mod_w,
                        const float* __restrict__ mod_b, float* __restrict__ sconv) {
    int wid  = blockIdx.x * 4 + (threadIdx.x >> 6);   // 0..4095 = b*512+i
    int lane = threadIdx.x & 63;
    int b = wid >> 9;
    int i = wid & 511;
    const float4* st = (const float4*)(style + (size_t)b * ZD);
    const float4* mw = (const float4*)(mod_w + (size_t)i * ZD);
    float4 a0 = st[lane],      b0 = mw[lane];
    float4 a1 = st[lane + 64], b1 = mw[lane + 64];
    float sum = a0.x*b0.x + a0.y*b0.y + a0.z*b0.z + a0.w*b0.w
              + a1.x*b1.x + a1.y*b1.y + a1.z*b1.z + a1.w*b1.w;
    #pragma unroll
    for (int off = 32; off > 0; off >>= 1) sum += __shfl_down(sum, off);
    if (lane == 0) sconv[wid] = (sum * MOD_SCALE + mod_b[i]) * CONV_SCALE;
}

// ---------------- K1: zero the 1-px border of padded xs2p [8][66][66][512] bf16
__global__ void k_zero_border(unsigned short* __restrict__ xs2p) {
    int b = blockIdx.y;
    int p = blockIdx.x * 4 + (threadIdx.x >> 6);   // 0..259
    int lane = threadIdx.x & 63;
    int h, w;
    if (p < 66)       { h = 0;       w = p; }
    else if (p < 132) { h = 65;      w = p - 66; }
    else if (p < 196) { h = p - 131; w = 0; }      // rows 1..64
    else              { h = p - 195; w = 65; }
    int4 z = {0, 0, 0, 0};
    *(int4*)&xs2p[((size_t)(b * 66 + h) * 66 + w) * 512 + lane * 8] = z;
}

// ---------------- K2: xs2p[b][h+1][w+1][i] = bf16(input[b][i][h][w] * sconv[b][i])
__global__ void k_scale_input(const float* __restrict__ input, const float* __restrict__ sconv,
                              unsigned short* __restrict__ xs2p) {
    int i0 = blockIdx.x * 32;
    int h  = blockIdx.y;
    int b  = blockIdx.z;
    __shared__ unsigned short lds[64][40];   // [w][ii], padded row
    #pragma unroll
    for (int r = 0; r < 8; ++r) {
        int ii = r * 4 + (threadIdx.x >> 6);
        int w  = threadIdx.x & 63;
        float v = input[(((size_t)b * CIN + i0 + ii) * HH + h) * WW + w];
        float s = sconv[b * CIN + i0 + ii];
        lds[w][ii] = f32_to_bf16_rne(v * s);
    }
    __syncthreads();
    int w = threadIdx.x >> 2, q = threadIdx.x & 3;
    int4 val = *(const int4*)&lds[w][q * 8];
    *(int4*)&xs2p[((size_t)(b * 66 + h + 1) * 66 + (w + 1)) * 512 + i0 + q * 8] = val;
}

// ---------------- K3: w3 ts-linear weights. ts = c*9+tap.
// byte addr = ts*32768 + half*16384 + (g*256 + oc_low)*16 ; elem += i&7
__global__ void k_weight(const float* __restrict__ weight, unsigned short* __restrict__ w3) {
    int t = blockIdx.x * 256 + threadIdx.x;   // 0 .. 512*512-1 : o*512 + i
    int o = t >> 9, i = t & 511;
    int c = i >> 5, g = (i >> 3) & 3, il = i & 7;
    int h = o >> 8, ol = o & 255;
    const float* src = weight + ((size_t)o * CIN + i) * 9;
    #pragma unroll
    for (int p = 0; p < 9; ++p) {
        size_t gran = ((size_t)(c * 9 + p) * 2 + h) * 1024 + g * 256 + ol;
        w3[gran * 8 + il] = f32_to_bf16_rne(src[p]);
    }
}

// ---------------- K4: main conv. 512 thr / 8 waves. Tile 256 OC x (4 rows x 64 px).
// Wave tile 128oc x 64px = 4mt x 2nt tiles of 32x32. One phase per ts (m201 sandwich):
// GLDs; 12 ds_read_b128; vmcnt(N); barrier; lgkmcnt(0)+sched_barrier; 16 MFMA; barrier.
// LDS: W 4x16KB rotating (lead 3) + X 2x32KB = 128KB.
#define GLD(srcp, ldsbyte)                                                        \
    __builtin_amdgcn_global_load_lds(                                             \
        (const __attribute__((address_space(1))) unsigned int*)(srcp),            \
        (__attribute__((address_space(3))) unsigned int*)(smb + (ldsbyte)),       \
        16, 0, 0)

#define TAP(t, VMA, DOX, DOW) {                                                   \
    const int kh_ = (t) / 3, kw_ = (t) % 3;                                       \
    const int wwr_ = (wrd + 49152) & 65535;                                       \
    if (DOW) { GLD(pW, wwr_ + wdst); GLD(pW + 8192, wwr_ + 8192 + wdst);          \
               pW += 32768; }                                                     \
    if ((DOX) && (t) == 0) { GLD(sxn +  0, xwr + 0 * 8192 + wdst);                \
                             GLD(sxn + 16, xwr + 1 * 8192 + wdst); }              \
    if ((DOX) && (t) == 1) { GLD(sxn + 32, xwr + 2 * 8192 + wdst);                \
                             GLD(sxn + 48, xwr + 3 * 8192 + wdst); }              \
    {   const char* wb = smb + wrd + aoff;                                        \
        const char* xb = smb + xrd + boff + kh_ * 1056 + kw_ * 16;                \
        aA[0] = *(const bf16x8*)(wb);        aA[1] = *(const bf16x8*)(wb + 512);  \
        aA[2] = *(const bf16x8*)(wb + 1024); aA[3] = *(const bf16x8*)(wb + 1536); \
        aB[0] = *(const bf16x8*)(wb + 8192);        aB[1] = *(const bf16x8*)(wb + 8704);  \
        aB[2] = *(const bf16x8*)(wb + 9216);        aB[3] = *(const bf16x8*)(wb + 9728);  \
        bA[0] = *(const bf16x8*)(xb);        bA[1] = *(const bf16x8*)(xb + 512);  \
        bB[0] = *(const bf16x8*)(xb + 16384); bB[1] = *(const bf16x8*)(xb + 16896); \
    }                                                                             \
    asm volatile("s_waitcnt vmcnt(" #VMA ")" ::: "memory");                       \
    __builtin_amdgcn_s_barrier();                                                 \
    asm volatile("s_waitcnt lgkmcnt(0)");                                         \
    __builtin_amdgcn_sched_barrier(0);                                            \
    __builtin_amdgcn_s_setprio(1);                                                \
    _Pragma("unroll") for (int mt = 0; mt < 4; ++mt)                              \
        _Pragma("unroll") for (int nt = 0; nt < 2; ++nt)                          \
            acc[mt][nt] = __builtin_amdgcn_mfma_f32_32x32x16_bf16(                \
                aA[mt], bA[nt], acc[mt][nt], 0, 0, 0);                            \
    _Pragma("unroll") for (int mt = 0; mt < 4; ++mt)                              \
        _Pragma("unroll") for (int nt = 0; nt < 2; ++nt)                          \
            acc[mt][nt] = __builtin_amdgcn_mfma_f32_32x32x16_bf16(                \
                aB[mt], bB[nt], acc[mt][nt], 0, 0, 0);                            \
    __builtin_amdgcn_s_setprio(0);                                                \
    __builtin_amdgcn_s_barrier();                                                 \
    wrd = (wrd + 16384) & 65535;                                                  \
}

__global__ __launch_bounds__(512, 2)
void k_conv(const unsigned short* __restrict__ xs2p, const unsigned short* __restrict__ w3,
            float* __restrict__ out) {
    __shared__ unsigned short smem[65536];   // 131072 bytes: W 0..64K, X 64K..128K
    char* smb = (char*)smem;

    const int tid  = threadIdx.x;
    const int wid  = tid >> 6, lane = tid & 63;
    const int wm   = wid >> 2, wr   = wid & 3;
    const int l31  = lane & 31, l5  = lane >> 5;
    const int half = blockIdx.x;              // 0,1 -> oc0 = half*256
    const int oc0  = half * 256;
    const int y0   = blockIdx.y * 4;
    const int b    = blockIdx.z;

    const int p_lin = wid * 64 + lane;               // 0..511
    const int xrow  = p_lin / 66;
    const int xcol  = p_lin - xrow * 66;
    const char* srcX = (const char*)xs2p;
    if (p_lin < 396)
        srcX += ((size_t)(b * 66 + y0 + xrow) * 66 + xcol) * 1024;  // 1KB per pixel

    const char* pW0 = (const char*)w3 + (size_t)half * 16384 + p_lin * 16;
    const int wdst = p_lin * 16;                     // wave-linear LDS slice

    // ---- prologue FIFO: X(0) p0..p3, then W ts0,ts1,ts2
    GLD(srcX +  0, 65536 + 0 * 8192 + wdst);
    GLD(srcX + 16, 65536 + 1 * 8192 + wdst);
    GLD(srcX + 32, 65536 + 2 * 8192 + wdst);
    GLD(srcX + 48, 65536 + 3 * 8192 + wdst);
    GLD(pW0,          0     + wdst);
    GLD(pW0 +  8192,  8192  + wdst);
    GLD(pW0 + 32768,  16384 + wdst);
    GLD(pW0 + 40960,  24576 + wdst);
    GLD(pW0 + 65536,  32768 + wdst);
    GLD(pW0 + 73728,  40960 + wdst);
    const char* pW = pW0 + 3 * 32768;                // -> W(ts=3)
    asm volatile("s_waitcnt vmcnt(4)" ::: "memory"); // X(0) + W0 landed; W1,W2 in flight
    __builtin_amdgcn_s_barrier();

    f32x16 acc[4][2];
    #pragma unroll
    for (int mt = 0; mt < 4; ++mt)
        #pragma unroll
        for (int nt = 0; nt < 2; ++nt)
            acc[mt][nt] = (f32x16)(0.f);

    const int aoff = l5 * 4096 + (wm * 128 + l31) * 16;   // W frag base (bytes)
    const int boff = l5 * 8192 + (wr * 66 + l31) * 16;    // X frag base (bytes)

    bf16x8 aA[4], aB[4], bA[2], bB[2];
    int wrd = 0;             // W read buf = (ts&3)*16384
    int xrd = 65536;         // X read buf
    const char* sxn = srcX + 64;

    for (int c = 0; c < 15; ++c) {
        const int xwr = xrd ^ 32768;
        TAP(0, 6, 1, 1) TAP(1, 8, 1, 1) TAP(2, 8, 0, 1)
        TAP(3, 6, 0, 1) TAP(4, 4, 0, 1) TAP(5, 4, 0, 1)
        TAP(6, 4, 0, 1) TAP(7, 4, 0, 1) TAP(8, 4, 0, 1)
        sxn += 64; xrd ^= 32768;
    }
    {   // c = 15 tail: no X prefetch; last W GLD at tap5 (-> W143)
        const int xwr = 0; (void)xwr;
        TAP(0, 4, 0, 1) TAP(1, 4, 0, 1) TAP(2, 4, 0, 1)
        TAP(3, 4, 0, 1) TAP(4, 4, 0, 1) TAP(5, 4, 0, 1)
        TAP(6, 2, 0, 0) TAP(7, 0, 0, 0) TAP(8, 0, 0, 0)
    }

    // ---- epilogue: 32x32 C/D layout: col=lane&31, row=(reg&3)+8*(reg>>2)+4*(lane>>5)
    const int ybase = (y0 + wr) * 64;
    #pragma unroll
    for (int mt = 0; mt < 4; ++mt)
        #pragma unroll
        for (int nt = 0; nt < 2; ++nt)
            #pragma unroll
            for (int r = 0; r < 16; ++r) {
                int row = (r & 3) + 8 * (r >> 2) + 4 * l5;
                int oc  = oc0 + wm * 128 + mt * 32 + row;
                out[((size_t)(b * COUT + oc) << 12) + ybase + nt * 32 + l31] = acc[mt][nt][r];
            }
}

extern "C" void kernel_launch(void* const* d_in, const int* in_sizes, int n_in,
                              void* d_out, int out_size, void* d_ws, size_t ws_size,
                              hipStream_t stream) {
    const float* input  = (const float*)d_in[0];
    const float* style  = (const float*)d_in[1];
    const float* weight = (const float*)d_in[2];
    const float* mod_w  = (const float*)d_in[3];
    const float* mod_b  = (const float*)d_in[4];
    float* out = (float*)d_out;

    const size_t xs2p_bytes = (size_t)BB * 66 * 66 * 512 * 2;   // 35,684,352
    const size_t w3_bytes   = (size_t)144 * 2 * 1024 * 8 * 2;   // 4,718,592
    const size_t need = 16384 + xs2p_bytes + w3_bytes;
    if (ws_size < need) return;   // leave output poisoned -> clear failure

    float*          sconv = (float*)d_ws;
    unsigned short* xs2p  = (unsigned short*)((char*)d_ws + 16384);
    unsigned short* w3    = (unsigned short*)((char*)d_ws + 16384 + xs2p_bytes);

    hipLaunchKernelGGL(k_style,       dim3(1024),      dim3(256), 0, stream, style, mod_w, mod_b, sconv);
    hipLaunchKernelGGL(k_weight,      dim3(1024),      dim3(256), 0, stream, weight, w3);
    hipLaunchKernelGGL(k_zero_border, dim3(65, 8),     dim3(256), 0, stream, xs2p);
    hipLaunchKernelGGL(k_scale_input, dim3(16, 64, 8), dim3(256), 0, stream, input, sconv, xs2p);
    hipLaunchKernelGGL(k_conv,        dim3(2, 16, 8),  dim3(512), 0, stream, xs2p, w3, out);
}

// Round 6
// 161.891 us; speedup vs baseline: 1.0247x; 1.0140x over previous
//
#include <hip/hip_runtime.h>
#include <hip/hip_bf16.h>

#define BB   8
#define CIN  512
#define COUT 512
#define ZD   512
#define HH   64
#define WW   64

#define MOD_SCALE  0.04419417382415922f    // 1/sqrt(512)
#define CONV_SCALE 0.014731391274719742f   // 1/sqrt(512*9)

typedef __bf16 bf16x8 __attribute__((ext_vector_type(8)));
typedef float  f32x4  __attribute__((ext_vector_type(4)));
typedef float  f32x16 __attribute__((ext_vector_type(16)));

static __device__ __forceinline__ unsigned short f32_to_bf16_rne(float f) {
    unsigned int u = __float_as_uint(f);
    u = (u + 0x7FFFu + ((u >> 16) & 1u)) >> 16;
    return (unsigned short)u;
}

// ---------------- K0: sconv[b][i] = (style[b]·mod_w[i]*MOD_SCALE + mod_b[i]) * CONV_SCALE
__global__ void k_style(const float* __restrict__ style, const float* __restrict__ mod_w,
                        const float* __restrict__ mod_b, float* __restrict__ sconv) {
    int wid  = blockIdx.x * 4 + (threadIdx.x >> 6);   // 0..4095 = b*512+i
    int lane = threadIdx.x & 63;
    int b = wid >> 9;
    int i = wid & 511;
    const float4* st = (const float4*)(style + (size_t)b * ZD);
    const float4* mw = (const float4*)(mod_w + (size_t)i * ZD);
    float4 a0 = st[lane],      b0 = mw[lane];
    float4 a1 = st[lane + 64], b1 = mw[lane + 64];
    float sum = a0.x*b0.x + a0.y*b0.y + a0.z*b0.z + a0.w*b0.w
              + a1.x*b1.x + a1.y*b1.y + a1.z*b1.z + a1.w*b1.w;
    #pragma unroll
    for (int off = 32; off > 0; off >>= 1) sum += __shfl_down(sum, off);
    if (lane == 0) sconv[wid] = (sum * MOD_SCALE + mod_b[i]) * CONV_SCALE;
}

// ---------------- K1: zero the 1-px border of padded xs2p [8][66][66][512] bf16
__global__ void k_zero_border(unsigned short* __restrict__ xs2p) {
    int b = blockIdx.y;
    int p = blockIdx.x * 4 + (threadIdx.x >> 6);   // 0..259
    int lane = threadIdx.x & 63;
    int h, w;
    if (p < 66)       { h = 0;       w = p; }
    else if (p < 132) { h = 65;      w = p - 66; }
    else if (p < 196) { h = p - 131; w = 0; }      // rows 1..64
    else              { h = p - 195; w = 65; }
    int4 z = {0, 0, 0, 0};
    *(int4*)&xs2p[((size_t)(b * 66 + h) * 66 + w) * 512 + lane * 8] = z;
}

// ---------------- K2: xs2p[b][h+1][w+1][i] = bf16(input[b][i][h][w] * sconv[b][i])
__global__ void k_scale_input(const float* __restrict__ input, const float* __restrict__ sconv,
                              unsigned short* __restrict__ xs2p) {
    int i0 = blockIdx.x * 32;
    int h  = blockIdx.y;
    int b  = blockIdx.z;
    __shared__ unsigned short lds[64][40];   // [w][ii], padded row
    #pragma unroll
    for (int r = 0; r < 8; ++r) {
        int ii = r * 4 + (threadIdx.x >> 6);
        int w  = threadIdx.x & 63;
        float v = input[(((size_t)b * CIN + i0 + ii) * HH + h) * WW + w];
        float s = sconv[b * CIN + i0 + ii];
        lds[w][ii] = f32_to_bf16_rne(v * s);
    }
    __syncthreads();
    int w = threadIdx.x >> 2, q = threadIdx.x & 3;
    int4 val = *(const int4*)&lds[w][q * 8];
    *(int4*)&xs2p[((size_t)(b * 66 + h + 1) * 66 + (w + 1)) * 512 + i0 + q * 8] = val;
}

// ---------------- K3: w3 ts-linear weights. ts = c*9+tap.
// byte addr = ts*32768 + half*16384 + (g*256 + oc_low)*16 ; elem += i&7
__global__ void k_weight(const float* __restrict__ weight, unsigned short* __restrict__ w3) {
    int t = blockIdx.x * 256 + threadIdx.x;   // 0 .. 512*512-1 : o*512 + i
    int o = t >> 9, i = t & 511;
    int c = i >> 5, g = (i >> 3) & 3, il = i & 7;
    int h = o >> 8, ol = o & 255;
    const float* src = weight + ((size_t)o * CIN + i) * 9;
    #pragma unroll
    for (int p = 0; p < 9; ++p) {
        size_t gran = ((size_t)(c * 9 + p) * 2 + h) * 1024 + g * 256 + ol;
        w3[gran * 8 + il] = f32_to_bf16_rne(src[p]);
    }
}

// ---------------- K4: main conv. 512 thr / 8 waves. Tile 256 OC x (4 rows x 64 px).
// Cross-ts register pipeline: at ts, read H1(ts) + H0(ts+1) interleaved INTO the
// 16-MFMA stream via sched_group_barrier; one counted-vmcnt + one barrier per ts.
// LDS: W 4x16KB rotating (lead 3) + X 2x32KB = 128KB.
#define GLD(srcp, ldsbyte)                                                        \
    __builtin_amdgcn_global_load_lds(                                             \
        (const __attribute__((address_space(1))) unsigned int*)(srcp),            \
        (__attribute__((address_space(3))) unsigned int*)(smb + (ldsbyte)),       \
        16, 0, 0)

#define TAP(t, VMA, DOX, DOW, DONEXT, C, N) {                                     \
    const int wwr_ = (wrd + 49152) & 65535;                                       \
    if (DOW) { GLD(pW, wwr_ + wdst); GLD(pW + 8192, wwr_ + 8192 + wdst);          \
               pW += 32768; }                                                     \
    if ((DOX) && (t) == 0) { GLD(sxn +  0, (xrd ^ 32768) + 0 * 8192 + wdst);      \
                             GLD(sxn + 16, (xrd ^ 32768) + 1 * 8192 + wdst); }    \
    if ((DOX) && (t) == 1) { GLD(sxn + 32, (xrd ^ 32768) + 2 * 8192 + wdst);      \
                             GLD(sxn + 48, (xrd ^ 32768) + 3 * 8192 + wdst); }    \
    { /* in-phase H1 reads (current tap, ch 16..31) */                            \
      const int kh_ = (t) / 3, kw_ = (t) % 3;                                     \
      const char* wb1 = smb + wrd + 8192 + aoff;                                  \
      const char* xb1 = smb + xrd + 16384 + boff + kh_ * 1056 + kw_ * 16;         \
      a1[0] = *(const bf16x8*)(wb1);         a1[1] = *(const bf16x8*)(wb1 + 512); \
      a1[2] = *(const bf16x8*)(wb1 + 1024);  a1[3] = *(const bf16x8*)(wb1 + 1536);\
      b1[0] = *(const bf16x8*)(xb1);         b1[1] = *(const bf16x8*)(xb1 + 512); \
    }                                                                             \
    if (DONEXT) { /* next-ts H0 reads (ch 0..15 of tap t+1) */                    \
      const int tn_  = ((t) + 1) % 9;                                             \
      const int khn_ = tn_ / 3, kwn_ = tn_ % 3;                                   \
      const int wrdn_ = (wrd + 16384) & 65535;                                    \
      const int xrdn_ = ((t) == 8) ? (xrd ^ 32768) : xrd;                         \
      const char* wb0 = smb + wrdn_ + aoff;                                       \
      const char* xb0 = smb + xrdn_ + boff + khn_ * 1056 + kwn_ * 16;             \
      a0##N[0] = *(const bf16x8*)(wb0);        a0##N[1] = *(const bf16x8*)(wb0 + 512); \
      a0##N[2] = *(const bf16x8*)(wb0 + 1024); a0##N[3] = *(const bf16x8*)(wb0 + 1536);\
      b0##N[0] = *(const bf16x8*)(xb0);        b0##N[1] = *(const bf16x8*)(xb0 + 512); \
    }                                                                             \
    __builtin_amdgcn_s_setprio(1);                                                \
    _Pragma("unroll") for (int mt = 0; mt < 4; ++mt)                              \
        _Pragma("unroll") for (int nt = 0; nt < 2; ++nt)                          \
            acc[mt][nt] = __builtin_amdgcn_mfma_f32_32x32x16_bf16(                \
                a0##C[mt], b0##C[nt], acc[mt][nt], 0, 0, 0);                      \
    _Pragma("unroll") for (int mt = 0; mt < 4; ++mt)                              \
        _Pragma("unroll") for (int nt = 0; nt < 2; ++nt)                          \
            acc[mt][nt] = __builtin_amdgcn_mfma_f32_32x32x16_bf16(                \
                a1[mt], b1[nt], acc[mt][nt], 0, 0, 0);                            \
    __builtin_amdgcn_s_setprio(0);                                                \
    __builtin_amdgcn_sched_group_barrier(0x100, 3, 0);                            \
    __builtin_amdgcn_sched_group_barrier(0x008, 4, 0);                            \
    __builtin_amdgcn_sched_group_barrier(0x100, 3, 0);                            \
    __builtin_amdgcn_sched_group_barrier(0x008, 4, 0);                            \
    __builtin_amdgcn_sched_group_barrier(0x100, 3, 0);                            \
    __builtin_amdgcn_sched_group_barrier(0x008, 4, 0);                            \
    __builtin_amdgcn_sched_group_barrier(0x100, 3, 0);                            \
    __builtin_amdgcn_sched_group_barrier(0x008, 4, 0);                            \
    asm volatile("s_waitcnt vmcnt(" #VMA ")" ::: "memory");                       \
    __builtin_amdgcn_s_barrier();                                                 \
    wrd = (wrd + 16384) & 65535;                                                  \
}

#define CHUNK_STD(S, N)                                                           \
    TAP(0, 4, 1, 1, 1, S, N) TAP(1, 4, 1, 1, 1, N, S) TAP(2, 2, 1, 1, 1, S, N)    \
    TAP(3, 2, 1, 1, 1, N, S) TAP(4, 2, 1, 1, 1, S, N) TAP(5, 2, 1, 1, 1, N, S)    \
    TAP(6, 2, 1, 1, 1, S, N) TAP(7, 2, 1, 1, 1, N, S) TAP(8, 2, 1, 1, 1, S, N)

__global__ __launch_bounds__(512, 2)
void k_conv(const unsigned short* __restrict__ xs2p, const unsigned short* __restrict__ w3,
            float* __restrict__ out) {
    __shared__ unsigned short smem[65536];   // 131072 bytes: W 0..64K, X 64K..128K
    char* smb = (char*)smem;

    const int tid  = threadIdx.x;
    const int wid  = tid >> 6, lane = tid & 63;
    const int wm   = wid >> 2, wr   = wid & 3;
    const int l31  = lane & 31, l5  = lane >> 5;
    const int half = blockIdx.x;              // 0,1 -> oc0 = half*256
    const int oc0  = half * 256;
    const int y0   = blockIdx.y * 4;
    const int b    = blockIdx.z;

    const int p_lin = wid * 64 + lane;               // 0..511
    const int xrow  = p_lin / 66;
    const int xcol  = p_lin - xrow * 66;
    const char* srcX = (const char*)xs2p;
    if (p_lin < 396)
        srcX += ((size_t)(b * 66 + y0 + xrow) * 66 + xcol) * 1024;  // 1KB per pixel

    const char* pW0 = (const char*)w3 + (size_t)half * 16384 + p_lin * 16;
    const int wdst = p_lin * 16;                     // wave-linear LDS slice

    // ---- prologue FIFO: X(0) p0..p3, then W ts0,ts1,ts2
    GLD(srcX +  0, 65536 + 0 * 8192 + wdst);
    GLD(srcX + 16, 65536 + 1 * 8192 + wdst);
    GLD(srcX + 32, 65536 + 2 * 8192 + wdst);
    GLD(srcX + 48, 65536 + 3 * 8192 + wdst);
    GLD(pW0,          0     + wdst);
    GLD(pW0 +  8192,  8192  + wdst);
    GLD(pW0 + 32768,  16384 + wdst);
    GLD(pW0 + 40960,  24576 + wdst);
    GLD(pW0 + 65536,  32768 + wdst);
    GLD(pW0 + 73728,  40960 + wdst);
    const char* pW = pW0 + 3 * 32768;                // -> W(ts=3)
    asm volatile("s_waitcnt vmcnt(4)" ::: "memory"); // X(0) + W0 landed; W1,W2 in flight
    __builtin_amdgcn_s_barrier();

    f32x16 acc[4][2];
    #pragma unroll
    for (int mt = 0; mt < 4; ++mt)
        #pragma unroll
        for (int nt = 0; nt < 2; ++nt)
            acc[mt][nt] = (f32x16)(0.f);

    const int aoff = l5 * 4096 + (wm * 128 + l31) * 16;   // W frag base (bytes)
    const int boff = l5 * 8192 + (wr * 66 + l31) * 16;    // X frag base (bytes)

    bf16x8 a0E[4], b0E[2], a0O[4], b0O[2], a1[4], b1[2];
    int wrd = 0;             // W read buf = (ts&3)*16384
    int xrd = 65536;         // X read buf
    const char* sxn = srcX + 64;

    // ---- pre-read H0(ts0) into E: W0 granules g0/g1, X chunk0 tap0
    {
        const char* wb = smb + aoff;
        const char* xb = smb + 65536 + boff;
        a0E[0] = *(const bf16x8*)(wb);         a0E[1] = *(const bf16x8*)(wb + 512);
        a0E[2] = *(const bf16x8*)(wb + 1024);  a0E[3] = *(const bf16x8*)(wb + 1536);
        b0E[0] = *(const bf16x8*)(xb);         b0E[1] = *(const bf16x8*)(xb + 512);
    }

    for (int c2 = 0; c2 < 7; ++c2) {
        CHUNK_STD(E, O) sxn += 64; xrd ^= 32768;   // even chunk
        CHUNK_STD(O, E) sxn += 64; xrd ^= 32768;   // odd chunk
    }
    CHUNK_STD(E, O) sxn += 64; xrd ^= 32768;       // c = 14 (stages X of c15)
    // c = 15 tail (starts on O): last W GLD at tap5 (-> W143); no X prefetch
    TAP(0, 2, 0, 1, 1, O, E) TAP(1, 2, 0, 1, 1, E, O) TAP(2, 2, 0, 1, 1, O, E)
    TAP(3, 2, 0, 1, 1, E, O) TAP(4, 2, 0, 1, 1, O, E) TAP(5, 2, 0, 1, 1, E, O)
    TAP(6, 0, 0, 0, 1, O, E) TAP(7, 0, 0, 0, 1, E, O) TAP(8, 0, 0, 0, 0, O, E)

    // ---- epilogue: 32x32 C/D layout: col=lane&31, row=(reg&3)+8*(reg>>2)+4*(lane>>5)
    const int ybase = (y0 + wr) * 64;
    #pragma unroll
    for (int mt = 0; mt < 4; ++mt)
        #pragma unroll
        for (int nt = 0; nt < 2; ++nt)
            #pragma unroll
            for (int r = 0; r < 16; ++r) {
                int row = (r & 3) + 8 * (r >> 2) + 4 * l5;
                int oc  = oc0 + wm * 128 + mt * 32 + row;
                out[((size_t)(b * COUT + oc) << 12) + ybase + nt * 32 + l31] = acc[mt][nt][r];
            }
}

extern "C" void kernel_launch(void* const* d_in, const int* in_sizes, int n_in,
                              void* d_out, int out_size, void* d_ws, size_t ws_size,
                              hipStream_t stream) {
    const float* input  = (const float*)d_in[0];
    const float* style  = (const float*)d_in[1];
    const float* weight = (const float*)d_in[2];
    const float* mod_w  = (const float*)d_in[3];
    const float* mod_b  = (const float*)d_in[4];
    float* out = (float*)d_out;

    const size_t xs2p_bytes = (size_t)BB * 66 * 66 * 512 * 2;   // 35,684,352
    const size_t w3_bytes   = (size_t)144 * 2 * 1024 * 8 * 2;   // 4,718,592
    const size_t need = 16384 + xs2p_bytes + w3_bytes;
    if (ws_size < need) return;   // leave output poisoned -> clear failure

    float*          sconv = (float*)d_ws;
    unsigned short* xs2p  = (unsigned short*)((char*)d_ws + 16384);
    unsigned short* w3    = (unsigned short*)((char*)d_ws + 16384 + xs2p_bytes);

    hipLaunchKernelGGL(k_style,       dim3(1024),      dim3(256), 0, stream, style, mod_w, mod_b, sconv);
    hipLaunchKernelGGL(k_weight,      dim3(1024),      dim3(256), 0, stream, weight, w3);
    hipLaunchKernelGGL(k_zero_border, dim3(65, 8),     dim3(256), 0, stream, xs2p);
    hipLaunchKernelGGL(k_scale_input, dim3(16, 64, 8), dim3(256), 0, stream, input, sconv, xs2p);
    hipLaunchKernelGGL(k_conv,        dim3(2, 16, 8),  dim3(512), 0, stream, xs2p, w3, out);
}